// Round 2
// baseline (14999.455 us; speedup 1.0000x reference)
//
#include <hip/hip_runtime.h>
#include <math.h>

#define BB   512
#define TT   256
#define HH   512
#define DIN  514
#define DOUTN 2
#define DT   0.1f

#define NSLICE 16   // j-slices of 32 columns
#define NGROUP 16   // batch groups of 32 batches
#define SLW    32   // slice width (columns per WG)
#define BG     32   // batches per group

__device__ __forceinline__ float retanh_f(float a) {
    float t = tanhf(a);
    return t > 0.0f ? t : 0.0f;
}

// ---------------------------------------------------------------------------
// Kernel 1: transposes (one-time)
// ---------------------------------------------------------------------------
__global__ void transpose_w(const float* __restrict__ Wx, const float* __restrict__ Wh,
                            float* __restrict__ WxT, float* __restrict__ WhT) {
    int idx = blockIdx.x * 256 + threadIdx.x;
    if (idx < DIN * HH) {
        int d = idx / HH, j = idx % HH;
        WxT[idx] = Wx[j * DIN + d];
    } else {
        int idx2 = idx - DIN * HH;
        if (idx2 < HH * HH) {
            int k = idx2 / HH, j = idx2 % HH;
            WhT[idx2] = Wh[j * HH + k];
        }
    }
}

// ---------------------------------------------------------------------------
// Kernel 2: x2ah = x @ WxT + b  (written into hstore region, consumed by scan)
// ---------------------------------------------------------------------------
__global__ __launch_bounds__(256) void x2ah_kernel(const float* __restrict__ X,
                                                   const float* __restrict__ WxT,
                                                   const float* __restrict__ bias,
                                                   float* __restrict__ outr) {
    __shared__ float xs[16][516];
    const int tid = threadIdx.x;
    const int r0  = blockIdx.x * 16;

    #pragma unroll
    for (int m = 0; m < 16; ++m) {
        const float* xr = X + (r0 + m) * DIN;
        xs[m][tid]       = xr[tid];
        xs[m][tid + 256] = xr[tid + 256];
        if (tid < 2) xs[m][512 + tid] = xr[512 + tid];
    }
    __syncthreads();

    const int j = 2 * tid;
    const float2 bv = *(const float2*)&bias[j];
    float acc[16][2];
    #pragma unroll
    for (int m = 0; m < 16; ++m) { acc[m][0] = bv.x; acc[m][1] = bv.y; }

    for (int d = 0; d < 512; d += 4) {
        const float2 w0 = *(const float2*)&WxT[(d + 0) * HH + j];
        const float2 w1 = *(const float2*)&WxT[(d + 1) * HH + j];
        const float2 w2 = *(const float2*)&WxT[(d + 2) * HH + j];
        const float2 w3 = *(const float2*)&WxT[(d + 3) * HH + j];
        #pragma unroll
        for (int m = 0; m < 16; ++m) {
            const float4 xv = *(const float4*)&xs[m][d];
            acc[m][0] += xv.x * w0.x; acc[m][1] += xv.x * w0.y;
            acc[m][0] += xv.y * w1.x; acc[m][1] += xv.y * w1.y;
            acc[m][0] += xv.z * w2.x; acc[m][1] += xv.z * w2.y;
            acc[m][0] += xv.w * w3.x; acc[m][1] += xv.w * w3.y;
        }
    }
    {
        const float2 wa = *(const float2*)&WxT[512 * HH + j];
        const float2 wb = *(const float2*)&WxT[513 * HH + j];
        #pragma unroll
        for (int m = 0; m < 16; ++m) {
            acc[m][0] += xs[m][512] * wa.x; acc[m][1] += xs[m][512] * wa.y;
            acc[m][0] += xs[m][513] * wb.x; acc[m][1] += xs[m][513] * wb.y;
        }
    }
    #pragma unroll
    for (int m = 0; m < 16; ++m) {
        *(float2*)&outr[(r0 + m) * HH + j] = make_float2(acc[m][0], acc[m][1]);
    }
}

// ---------------------------------------------------------------------------
// Kernel 3: scan with W resident in LDS + per-group cross-WG h exchange.
// Grid 256 WGs (16 slices x 16 groups) x 512 threads, 1 WG/CU (128 KB LDS).
// Launched cooperatively so all 256 WGs are guaranteed co-resident.
//   hio: x2ah on read, h on write (same buffer, same index, same thread)
//   hbuf: [2][512b][512j] fp32 exchange buffer (double-buffered on t parity)
//   cnt:  [16 groups][256 steps] arrival counters (zeroed before launch)
// ---------------------------------------------------------------------------
__global__ __launch_bounds__(512) void scan2_kernel(const float* __restrict__ WhT,
                                                    const float* __restrict__ noise,
                                                    const float* __restrict__ ah0,
                                                    float* hio,
                                                    float* hbuf,
                                                    unsigned int* cnt) {
    __shared__ float ws[512][SLW];   // W_h^T slice: ws[k][jj] = Wh[jg][k]
    __shared__ float hs[BG][512];    // group's h state, all 512 columns

    const int tid = threadIdx.x;
    const int bid = blockIdx.x;
    const int js  = bid & (NSLICE - 1);   // column slice
    const int g   = bid >> 4;             // batch group
    const int b   = tid >> 4;             // local batch 0..31
    const int j   = (tid & 15) * 2;       // local column (pair)
    const int jg  = js * SLW + j;         // global column
    const int bgl = g * BG + b;           // global batch

    // one-time: W slice into LDS (coalesced rows of WhT)
    for (int idx = tid; idx < 512 * SLW; idx += 512) {
        int k = idx >> 5, jj = idx & (SLW - 1);
        ws[k][jj] = WhT[(k << 9) + js * SLW + jj];
    }
    // init h state: h_init[j] = retanh(ah0[j]), same for every batch
    for (int idx = tid; idx < BG * 512; idx += 512) {
        int bb = idx >> 9, jj = idx & 511;
        hs[bb][jj] = retanh_f(ah0[jj]);
    }
    float2 ah;
    ah.x = ah0[jg];
    ah.y = ah0[jg + 1];
    __syncthreads();

    unsigned int* mycnt = cnt + g * 256;

    for (int t = 0; t < TT; ++t) {
        if (t > 0) {
            // wait for all 16 slice-WGs of this group to publish step t-1
            if (tid == 0) {
                while (__hip_atomic_load(&mycnt[t - 1], __ATOMIC_ACQUIRE,
                                         __HIP_MEMORY_SCOPE_AGENT) < NSLICE)
                    __builtin_amdgcn_s_sleep(2);
            }
            __syncthreads();
            // reload group's full h (32 x 512) from hbuf[(t-1)&1], LLC-coherent
            const unsigned long long* src = (const unsigned long long*)
                (hbuf + (((t - 1) & 1) << 18) + (g << 14));
            for (int i = tid; i < BG * 256; i += 512) {
                unsigned long long u = __hip_atomic_load(&src[i], __ATOMIC_RELAXED,
                                                         __HIP_MEMORY_SCOPE_AGENT);
                float2 v;
                __builtin_memcpy(&v, &u, 8);
                int bb = i >> 8, jj = (i & 255) << 1;
                *(float2*)&hs[bb][jj] = v;
            }
            __syncthreads();
        }

        // prefetch this step's input drive + noise (hidden under the GEMM)
        const int gidx = (bgl * TT + t) * HH + jg;
        const float2 x2 = *(const float2*)&hio[gidx];
        const float2 nz = *(const float2*)&noise[gidx];

        // 32x32 patch GEMM over k=512, all operands LDS-resident
        float a0x = 0.f, a0y = 0.f, a1x = 0.f, a1y = 0.f;
        #pragma unroll 16
        for (int k = 0; k < 512; k += 4) {
            const float4 hv = *(const float4*)&hs[b][k];
            const float2 w0 = *(const float2*)&ws[k + 0][j];
            const float2 w1 = *(const float2*)&ws[k + 1][j];
            const float2 w2 = *(const float2*)&ws[k + 2][j];
            const float2 w3 = *(const float2*)&ws[k + 3][j];
            a0x += hv.x * w0.x; a0y += hv.x * w0.y;
            a1x += hv.y * w1.x; a1y += hv.y * w1.y;
            a0x += hv.z * w2.x; a0y += hv.z * w2.y;
            a1x += hv.w * w3.x; a1y += hv.w * w3.y;
        }
        const float accx = a0x + a1x;
        const float accy = a0y + a1y;

        // state update
        ah.x += DT * (accx + x2.x - ah.x);
        ah.y += DT * (accy + x2.y - ah.y);
        const float h0 = retanh_f(ah.x) + nz.x;
        const float h1 = retanh_f(ah.y) + nz.y;

        // publish: hstore (HBM output) + hbuf[t&1] (LLC, for the group)
        *(float2*)&hio[gidx] = make_float2(h0, h1);
        float2 hv2 = make_float2(h0, h1);
        unsigned long long u;
        __builtin_memcpy(&u, &hv2, 8);
        unsigned long long* dst = (unsigned long long*)(hbuf + ((t & 1) << 18));
        __hip_atomic_store(&dst[bgl * 256 + (jg >> 1)], u, __ATOMIC_RELAXED,
                           __HIP_MEMORY_SCOPE_AGENT);
        __threadfence();
        __syncthreads();
        if (tid == 0)
            __hip_atomic_fetch_add(&mycnt[t], 1u, __ATOMIC_ACQ_REL,
                                   __HIP_MEMORY_SCOPE_AGENT);
    }
}

// ---------------------------------------------------------------------------
// Kernel 4: tiny output projection
// ---------------------------------------------------------------------------
__global__ __launch_bounds__(256) void out_kernel(const float* __restrict__ hstore,
                                                  const float* __restrict__ Wy,
                                                  float* __restrict__ out0) {
    const int wave = threadIdx.x >> 6;
    const int lane = threadIdx.x & 63;
    const int r = blockIdx.x * 4 + wave;

    const float4* hv4 = (const float4*)&hstore[r * HH];
    float a0 = 0.0f, a1 = 0.0f;
    #pragma unroll
    for (int u = 0; u < 2; ++u) {
        const int e = u * 64 + lane;
        const float4 h  = hv4[e];
        const float4 w0 = *(const float4*)&Wy[e * 4];
        const float4 w1 = *(const float4*)&Wy[HH + e * 4];
        a0 += h.x * w0.x + h.y * w0.y + h.z * w0.z + h.w * w0.w;
        a1 += h.x * w1.x + h.y * w1.y + h.z * w1.z + h.w * w1.w;
    }
    #pragma unroll
    for (int off = 32; off > 0; off >>= 1) {
        a0 += __shfl_xor(a0, off);
        a1 += __shfl_xor(a1, off);
    }
    if (lane == 0) {
        out0[r * 2]     = a0;
        out0[r * 2 + 1] = a1;
    }
}

// ---------------------------------------------------------------------------
extern "C" void kernel_launch(void* const* d_in, const int* in_sizes, int n_in,
                              void* d_out, int out_size, void* d_ws, size_t ws_size,
                              hipStream_t stream) {
    const float* x     = (const float*)d_in[0];  // [B,T,DIN]
    const float* noise = (const float*)d_in[1];  // [B,T,H]
    const float* Wx    = (const float*)d_in[2];  // [H,DIN]
    const float* bah   = (const float*)d_in[3];  // [H]
    const float* Wh    = (const float*)d_in[4];  // [H,H]
    const float* Wy    = (const float*)d_in[5];  // [DOUT,H]
    const float* ah0   = (const float*)d_in[6];  // [H]

    float* out0   = (float*)d_out;                   // [B,T,DOUT]
    float* hstore = (float*)d_out + BB * TT * DOUTN; // [B,T,H]

    float* WxT = (float*)d_ws;                       // [DIN,H]   1.05 MB
    float* WhT = WxT + DIN * HH;                     // [H,H]     1.0 MB
    float* hbuf = WhT + HH * HH;                     // [2][B][H] 2.0 MB
    unsigned int* cnt = (unsigned int*)(hbuf + 2 * BB * HH); // [16][256] 16 KB

    hipMemsetAsync(cnt, 0, NGROUP * TT * sizeof(unsigned int), stream);
    transpose_w<<<(DIN * HH + HH * HH + 255) / 256, 256, 0, stream>>>(Wx, Wh, WxT, WhT);
    x2ah_kernel<<<BB * TT / 16, 256, 0, stream>>>(x, WxT, bah, hstore);

    {
        const float* whtp = WhT;
        float* hiop = hstore;
        void* args[] = { (void*)&whtp, (void*)&noise, (void*)&ah0,
                         (void*)&hiop, (void*)&hbuf, (void*)&cnt };
        hipLaunchCooperativeKernel((void*)scan2_kernel, dim3(NSLICE * NGROUP),
                                   dim3(512), args, 0, stream);
    }

    out_kernel<<<BB * TT / 4, 256, 0, stream>>>(hstore, Wy, out0);
}

// Round 3
// 3412.259 us; speedup vs baseline: 4.3958x; 4.3958x over previous
//
#include <hip/hip_runtime.h>
#include <math.h>

#define BB   512
#define TT   256
#define HH   512
#define DIN  514
#define DOUTN 2
#define DT   0.1f

#define MB   4     // batches per WG (scan)
#define NW   8     // waves per WG (scan): 512 threads

__device__ __forceinline__ float retanh_f(float a) {
    float t = tanhf(a);
    return t > 0.0f ? t : 0.0f;
}

__device__ __forceinline__ float readlane_f(float v, int lane) {
    union { float f; int i; } u; u.f = v;
    u.i = __builtin_amdgcn_readlane(u.i, lane);
    return u.f;
}

// ---------------------------------------------------------------------------
// Kernel 1: WxT[d][j] = Wx[j][d]  (for x2ah)
//           Wr repack of Wh^T for the scan:
//           col j = 64*c + l  ->  row-k slot  p = l*4 + (c&3) + (c>=4)*256
//           so lane l's two float4 loads cover cols {l+64m} m=0..7.
// ---------------------------------------------------------------------------
__global__ void transpose_w(const float* __restrict__ Wx, const float* __restrict__ Wh,
                            float* __restrict__ WxT, float* __restrict__ Wr) {
    int idx = blockIdx.x * 256 + threadIdx.x;
    if (idx < DIN * HH) {
        int d = idx / HH, j = idx % HH;
        WxT[idx] = Wx[j * DIN + d];
    } else {
        int idx2 = idx - DIN * HH;
        if (idx2 < HH * HH) {
            int j = idx2 >> 9, k = idx2 & 511;   // reads Wh[j][k] coalesced in k
            int c = j >> 6, l = j & 63;
            int p = l * 4 + (c & 3) + ((c >> 2) << 8);
            Wr[k * HH + p] = Wh[idx2];
        }
    }
}

// ---------------------------------------------------------------------------
// Kernel 2: x2ah = x @ WxT + b (into hstore region; consumed+overwritten by scan)
// ---------------------------------------------------------------------------
__global__ __launch_bounds__(256) void x2ah_kernel(const float* __restrict__ X,
                                                   const float* __restrict__ WxT,
                                                   const float* __restrict__ bias,
                                                   float* __restrict__ outr) {
    __shared__ float xs[16][516];
    const int tid = threadIdx.x;
    const int r0  = blockIdx.x * 16;

    #pragma unroll
    for (int m = 0; m < 16; ++m) {
        const float* xr = X + (r0 + m) * DIN;
        xs[m][tid]       = xr[tid];
        xs[m][tid + 256] = xr[tid + 256];
        if (tid < 2) xs[m][512 + tid] = xr[512 + tid];
    }
    __syncthreads();

    const int j = 2 * tid;
    const float2 bv = *(const float2*)&bias[j];
    float acc[16][2];
    #pragma unroll
    for (int m = 0; m < 16; ++m) { acc[m][0] = bv.x; acc[m][1] = bv.y; }

    for (int d = 0; d < 512; d += 4) {
        const float2 w0 = *(const float2*)&WxT[(d + 0) * HH + j];
        const float2 w1 = *(const float2*)&WxT[(d + 1) * HH + j];
        const float2 w2 = *(const float2*)&WxT[(d + 2) * HH + j];
        const float2 w3 = *(const float2*)&WxT[(d + 3) * HH + j];
        #pragma unroll
        for (int m = 0; m < 16; ++m) {
            const float4 xv = *(const float4*)&xs[m][d];
            acc[m][0] += xv.x * w0.x; acc[m][1] += xv.x * w0.y;
            acc[m][0] += xv.y * w1.x; acc[m][1] += xv.y * w1.y;
            acc[m][0] += xv.z * w2.x; acc[m][1] += xv.z * w2.y;
            acc[m][0] += xv.w * w3.x; acc[m][1] += xv.w * w3.y;
        }
    }
    {
        const float2 wa = *(const float2*)&WxT[512 * HH + j];
        const float2 wb = *(const float2*)&WxT[513 * HH + j];
        #pragma unroll
        for (int m = 0; m < 16; ++m) {
            acc[m][0] += xs[m][512] * wa.x; acc[m][1] += xs[m][512] * wa.y;
            acc[m][0] += xs[m][513] * wb.x; acc[m][1] += xs[m][513] * wb.y;
        }
    }
    #pragma unroll
    for (int m = 0; m < 16; ++m) {
        *(float2*)&outr[(r0 + m) * HH + j] = make_float2(acc[m][0], acc[m][1]);
    }
}

// ---------------------------------------------------------------------------
// Kernel 3 (scan, Design C): 128 WGs x 512 thr, MB=4 batches/WG.
// Wave w owns k-range [64w,64w+64) and columns j=64w+lane; h state lives in
// registers (hv[b]); the k-broadcast is v_readlane (no LDS); W streamed from
// L2 once per WG per step via 2 coalesced float4/k with 8-deep reg prefetch;
// cross-wave k-reduction via 64KB LDS double buffer, 1 barrier/step.
// Dynamic LDS: 2*8*8*64*16B = 128 KB.
// ---------------------------------------------------------------------------
__global__ __launch_bounds__(512) void scan3_kernel(const float* __restrict__ Wr,
                                                    const float* __restrict__ noise,
                                                    const float* __restrict__ ah0,
                                                    float* __restrict__ hio) {
    extern __shared__ float4 part[];   // [2][v:8][c:8][lane:64] float4-over-b

    const int tid  = threadIdx.x;
    const int lane = tid & 63;
    const int w    = tid >> 6;
    const int b0   = blockIdx.x * MB;
    const int j    = (w << 6) + lane;

    // lane's W column base: row k has 128 float4; this lane reads [k*128+lane]
    // (cols l+64m, m=0..3) and [k*128+64+lane] (cols l+64m, m=4..7)
    const float4* Wv = (const float4*)Wr + (size_t)w * 8192 + lane;

    float ah[MB], hv[MB];
    {
        const float a0 = ah0[j];
        const float h0 = retanh_f(a0);
        #pragma unroll
        for (int b = 0; b < MB; ++b) { ah[b] = a0; hv[b] = h0; }
    }

    for (int t = 0; t < TT; ++t) {
        // early independent loads (consumed after the barrier)
        float x2[MB], nz[MB];
        #pragma unroll
        for (int b = 0; b < MB; ++b) {
            const int gidx = ((b0 + b) * TT + t) * HH + j;
            x2[b] = hio[gidx];
            nz[b] = noise[gidx];
        }

        float4 accA[MB], accB[MB];
        #pragma unroll
        for (int b = 0; b < MB; ++b) {
            accA[b] = make_float4(0.f, 0.f, 0.f, 0.f);
            accB[b] = make_float4(0.f, 0.f, 0.f, 0.f);
        }

        // prologue: fill 8-deep prefetch buffer (16 loads in flight)
        float4 wbA[8], wbB[8];
        const float4* pw = Wv;
        #pragma unroll
        for (int q = 0; q < 8; ++q) {
            wbA[q] = pw[q * 128];
            wbB[q] = pw[q * 128 + 64];
        }

        for (int blk = 0; blk < 7; ++blk) {
            #pragma unroll
            for (int q = 0; q < 8; ++q) {
                const int kk = (blk << 3) + q;
                const float4 wa = wbA[q];
                const float4 wb = wbB[q];
                wbA[q] = pw[(q + 8) * 128];
                wbB[q] = pw[(q + 8) * 128 + 64];
                #pragma unroll
                for (int b = 0; b < MB; ++b) {
                    const float s = readlane_f(hv[b], kk);
                    accA[b].x += s * wa.x; accA[b].y += s * wa.y;
                    accA[b].z += s * wa.z; accA[b].w += s * wa.w;
                    accB[b].x += s * wb.x; accB[b].y += s * wb.y;
                    accB[b].z += s * wb.z; accB[b].w += s * wb.w;
                }
            }
            pw += 1024;
        }
        #pragma unroll
        for (int q = 0; q < 8; ++q) {   // last block, no prefetch
            const int kk = 56 + q;
            const float4 wa = wbA[q];
            const float4 wb = wbB[q];
            #pragma unroll
            for (int b = 0; b < MB; ++b) {
                const float s = readlane_f(hv[b], kk);
                accA[b].x += s * wa.x; accA[b].y += s * wa.y;
                accA[b].z += s * wa.z; accA[b].w += s * wa.w;
                accB[b].x += s * wb.x; accB[b].y += s * wb.y;
                accB[b].z += s * wb.z; accB[b].w += s * wb.w;
            }
        }

        // write partials: part[pb][w][c][lane], contiguous 1KB per instr
        {
            float4* dst = part + (((size_t)(t & 1) * 8 + w) * 8) * 64 + lane;
            dst[0 * 64] = make_float4(accA[0].x, accA[1].x, accA[2].x, accA[3].x);
            dst[1 * 64] = make_float4(accA[0].y, accA[1].y, accA[2].y, accA[3].y);
            dst[2 * 64] = make_float4(accA[0].z, accA[1].z, accA[2].z, accA[3].z);
            dst[3 * 64] = make_float4(accA[0].w, accA[1].w, accA[2].w, accA[3].w);
            dst[4 * 64] = make_float4(accB[0].x, accB[1].x, accB[2].x, accB[3].x);
            dst[5 * 64] = make_float4(accB[0].y, accB[1].y, accB[2].y, accB[3].y);
            dst[6 * 64] = make_float4(accB[0].z, accB[1].z, accB[2].z, accB[3].z);
            dst[7 * 64] = make_float4(accB[0].w, accB[1].w, accB[2].w, accB[3].w);
        }
        __syncthreads();

        // reduce over the 8 waves' partials for my column (slot c = w)
        float4 sum;
        {
            const float4* src = part + ((size_t)(t & 1) * 64 + w) * 64 + lane;
            sum = src[0];
            #pragma unroll
            for (int v = 1; v < 8; ++v) {
                const float4 pv = src[(size_t)v * 512];
                sum.x += pv.x; sum.y += pv.y; sum.z += pv.z; sum.w += pv.w;
            }
        }

        const float sums[MB] = {sum.x, sum.y, sum.z, sum.w};
        #pragma unroll
        for (int b = 0; b < MB; ++b) {
            ah[b] += DT * (sums[b] + x2[b] - ah[b]);
            const float hn = retanh_f(ah[b]) + nz[b];
            hv[b] = hn;
            hio[((b0 + b) * TT + t) * HH + j] = hn;
        }
        // no second barrier: double-buffered `part` + the one barrier above
        // order writes(t+2,bufP) after reads(t,bufP) transitively.
    }
}

// ---------------------------------------------------------------------------
// Kernel 4: tiny output projection
// ---------------------------------------------------------------------------
__global__ __launch_bounds__(256) void out_kernel(const float* __restrict__ hstore,
                                                  const float* __restrict__ Wy,
                                                  float* __restrict__ out0) {
    const int wave = threadIdx.x >> 6;
    const int lane = threadIdx.x & 63;
    const int r = blockIdx.x * 4 + wave;

    const float4* hv4 = (const float4*)&hstore[r * HH];
    float a0 = 0.0f, a1 = 0.0f;
    #pragma unroll
    for (int u = 0; u < 2; ++u) {
        const int e = u * 64 + lane;
        const float4 h  = hv4[e];
        const float4 w0 = *(const float4*)&Wy[e * 4];
        const float4 w1 = *(const float4*)&Wy[HH + e * 4];
        a0 += h.x * w0.x + h.y * w0.y + h.z * w0.z + h.w * w0.w;
        a1 += h.x * w1.x + h.y * w1.y + h.z * w1.z + h.w * w1.w;
    }
    #pragma unroll
    for (int off = 32; off > 0; off >>= 1) {
        a0 += __shfl_xor(a0, off);
        a1 += __shfl_xor(a1, off);
    }
    if (lane == 0) {
        out0[r * 2]     = a0;
        out0[r * 2 + 1] = a1;
    }
}

// ---------------------------------------------------------------------------
extern "C" void kernel_launch(void* const* d_in, const int* in_sizes, int n_in,
                              void* d_out, int out_size, void* d_ws, size_t ws_size,
                              hipStream_t stream) {
    const float* x     = (const float*)d_in[0];  // [B,T,DIN]
    const float* noise = (const float*)d_in[1];  // [B,T,H]
    const float* Wx    = (const float*)d_in[2];  // [H,DIN]
    const float* bah   = (const float*)d_in[3];  // [H]
    const float* Wh    = (const float*)d_in[4];  // [H,H]
    const float* Wy    = (const float*)d_in[5];  // [DOUT,H]
    const float* ah0   = (const float*)d_in[6];  // [H]

    float* out0   = (float*)d_out;                   // [B,T,DOUT]
    float* hstore = (float*)d_out + BB * TT * DOUTN; // [B,T,H]

    float* WxT = (float*)d_ws;                       // [DIN,H]  1.05 MB
    float* Wr  = WxT + DIN * HH;                     // [H,H]    1.0 MB (repacked)

    transpose_w<<<(DIN * HH + HH * HH + 255) / 256, 256, 0, stream>>>(Wx, Wh, WxT, Wr);
    x2ah_kernel<<<BB * TT / 16, 256, 0, stream>>>(x, WxT, bah, hstore);
    scan3_kernel<<<BB / MB, 512, 131072, stream>>>(Wr, noise, ah0, hstore);
    out_kernel<<<BB * TT / 4, 256, 0, stream>>>(hstore, Wy, out0);
}

// Round 4
// 3148.292 us; speedup vs baseline: 4.7643x; 1.0838x over previous
//
#include <hip/hip_runtime.h>
#include <math.h>

#define BB   512
#define TT   256
#define HH   512
#define DIN  514
#define DOUTN 2
#define DT   0.1f

// ---- Design E (scan4) geometry ----
#define GW    8     // WGs per group (k-slices)
#define GB    16    // batches per group
#define SLICE 64    // k-rows / j-cols per slice
#define NGRP  32    // 512 / GB
#define HSPAD 20    // hs row stride (floats), 16B-aligned, breaks b-stride conflicts

// ---- Design C (scan3 fallback) geometry ----
#define MB   4

__device__ __forceinline__ float retanh_f(float a) {
    float t = tanhf(a);
    return t > 0.0f ? t : 0.0f;
}

__device__ __forceinline__ float readlane_f(float v, int lane) {
    union { float f; int i; } u; u.f = v;
    u.i = __builtin_amdgcn_readlane(u.i, lane);
    return u.f;
}

__device__ __forceinline__ void st8_agent(unsigned long long* p, float2 v) {
    unsigned long long u;
    __builtin_memcpy(&u, &v, 8);
    __hip_atomic_store(p, u, __ATOMIC_RELAXED, __HIP_MEMORY_SCOPE_AGENT);
}
__device__ __forceinline__ float2 ld8_agent(const unsigned long long* p) {
    unsigned long long u = __hip_atomic_load(p, __ATOMIC_RELAXED, __HIP_MEMORY_SCOPE_AGENT);
    float2 v;
    __builtin_memcpy(&v, &u, 8);
    return v;
}

// ---------------------------------------------------------------------------
// Kernel 1: WxT always; Wsec = plain WhT (repack=0, scan4) or Wr (repack=1, scan3)
// ---------------------------------------------------------------------------
__global__ void transpose_w(const float* __restrict__ Wx, const float* __restrict__ Wh,
                            float* __restrict__ WxT, float* __restrict__ Wsec, int repack) {
    int idx = blockIdx.x * 256 + threadIdx.x;
    if (idx < DIN * HH) {
        int d = idx / HH, j = idx % HH;
        WxT[idx] = Wx[j * DIN + d];
    } else {
        int idx2 = idx - DIN * HH;
        if (idx2 < HH * HH) {
            int j = idx2 >> 9, k = idx2 & 511;     // Wh[j][k], coalesced in k
            if (repack) {
                int c = j >> 6, l = j & 63;
                int p = l * 4 + (c & 3) + ((c >> 2) << 8);
                Wsec[k * HH + p] = Wh[idx2];
            } else {
                Wsec[k * HH + j] = Wh[idx2];       // WhT[k][j]
            }
        }
    }
}

// ---------------------------------------------------------------------------
// Kernel 2: x2ah = x @ WxT + b (into hstore region; consumed+overwritten by scan)
// ---------------------------------------------------------------------------
__global__ __launch_bounds__(256) void x2ah_kernel(const float* __restrict__ X,
                                                   const float* __restrict__ WxT,
                                                   const float* __restrict__ bias,
                                                   float* __restrict__ outr) {
    __shared__ float xs[16][516];
    const int tid = threadIdx.x;
    const int r0  = blockIdx.x * 16;

    #pragma unroll
    for (int m = 0; m < 16; ++m) {
        const float* xr = X + (r0 + m) * DIN;
        xs[m][tid]       = xr[tid];
        xs[m][tid + 256] = xr[tid + 256];
        if (tid < 2) xs[m][512 + tid] = xr[512 + tid];
    }
    __syncthreads();

    const int j = 2 * tid;
    const float2 bv = *(const float2*)&bias[j];
    float acc[16][2];
    #pragma unroll
    for (int m = 0; m < 16; ++m) { acc[m][0] = bv.x; acc[m][1] = bv.y; }

    for (int d = 0; d < 512; d += 4) {
        const float2 w0 = *(const float2*)&WxT[(d + 0) * HH + j];
        const float2 w1 = *(const float2*)&WxT[(d + 1) * HH + j];
        const float2 w2 = *(const float2*)&WxT[(d + 2) * HH + j];
        const float2 w3 = *(const float2*)&WxT[(d + 3) * HH + j];
        #pragma unroll
        for (int m = 0; m < 16; ++m) {
            const float4 xv = *(const float4*)&xs[m][d];
            acc[m][0] += xv.x * w0.x; acc[m][1] += xv.x * w0.y;
            acc[m][0] += xv.y * w1.x; acc[m][1] += xv.y * w1.y;
            acc[m][0] += xv.z * w2.x; acc[m][1] += xv.z * w2.y;
            acc[m][0] += xv.w * w3.x; acc[m][1] += xv.w * w3.y;
        }
    }
    {
        const float2 wa = *(const float2*)&WxT[512 * HH + j];
        const float2 wb = *(const float2*)&WxT[513 * HH + j];
        #pragma unroll
        for (int m = 0; m < 16; ++m) {
            acc[m][0] += xs[m][512] * wa.x; acc[m][1] += xs[m][512] * wa.y;
            acc[m][0] += xs[m][513] * wb.x; acc[m][1] += xs[m][513] * wb.y;
        }
    }
    #pragma unroll
    for (int m = 0; m < 16; ++m) {
        *(float2*)&outr[(r0 + m) * HH + j] = make_float2(acc[m][0], acc[m][1]);
    }
}

// ---------------------------------------------------------------------------
// Kernel 3 (Design E): k-split-8 scan. 256 WGs x 512 thr, cooperative.
// WG (g, me): group g (batches 16g..16g+15), k/j-slice me (cols 64me..64me+63).
// W slice [64k][512j] LDS-resident (loaded once). Per step:
//   GEMM: partial[16b][512j] (thread tile 4b x 4j, acc in regs)
//   publish: 8x 4KB chunks into peers' inboxes (relaxed agent 8B stores)
//   release: s_waitcnt vmcnt(0) + barrier + relaxed flag  (NO cache flushes)
//   poll 8 flags relaxed; read 8 float2/thread; update own h-slice.
// Inbox double-buffered by t-parity; flags pre-zeroed per launch.
// ---------------------------------------------------------------------------
__global__ __launch_bounds__(512) void scan4_kernel(const float* __restrict__ WhT,
                                                    const float* __restrict__ noise,
                                                    const float* __restrict__ ah0,
                                                    float* __restrict__ hio,
                                                    float* inbox,
                                                    unsigned int* flags) {
    __shared__ float wsL[SLICE * HH];      // 128 KB: ws[kk][j]
    __shared__ float hsL[SLICE * HSPAD];   // 5 KB:   hs[kk][b] (b<16, pad 20)

    const int tid  = threadIdx.x;
    const int gid  = blockIdx.x;           // 0..255
    const int g    = gid >> 3;             // group 0..31
    const int me   = gid & 7;              // slice 0..7
    const int bq   = tid >> 7;             // 0..3   (4 batch rows each)
    const int jq   = tid & 127;            // 0..127 (4 j cols each)
    const int b_loc = tid >> 5;            // 0..15  (exchange/update slot)
    const int jl    = (tid & 31) * 2;      // 0..62

    // one-time: W slice into LDS (coalesced)
    for (int idx = tid; idx < SLICE * HH; idx += 512)
        wsL[idx] = WhT[me * SLICE * HH + idx];

    // init h state for this slice (same for every batch)
    for (int idx = tid; idx < SLICE * GB; idx += 512) {
        int kk = idx >> 4, b = idx & 15;
        hsL[kk * HSPAD + b] = retanh_f(ah0[me * SLICE + kk]);
    }
    float2 ah;
    ah.x = ah0[me * SLICE + jl];
    ah.y = ah0[me * SLICE + jl + 1];
    __syncthreads();

    unsigned long long* ibx = (unsigned long long*)inbox;
    const size_t PARU = (size_t)256 * 8 * 16 * 64 / 2;   // u64 per parity buffer
    const int destg = g * 8 + (jq >> 4);                 // dest WG global id
    const int joff  = (jq & 15) * 4;

    for (int t = 0; t < TT; ++t) {
        const size_t pbase = (size_t)(t & 1) * PARU;

        // prefetch this step's input drive + noise (consumed after exchange)
        const int gidx = ((g * GB + b_loc) * TT + t) * HH + me * SLICE + jl;
        const float2 x2 = *(const float2*)&hio[gidx];
        const float2 nz = *(const float2*)&noise[gidx];

        // ---- GEMM: acc[r][c] = sum_kk hs[kk][4bq+r] * ws[kk][4jq+c] ----
        float4 a0 = {0,0,0,0}, a1 = {0,0,0,0}, a2 = {0,0,0,0}, a3 = {0,0,0,0};
        #pragma unroll 8
        for (int kk = 0; kk < SLICE; ++kk) {
            const float4 hv = *(const float4*)&hsL[kk * HSPAD + bq * 4]; // broadcast
            const float4 wv = *(const float4*)&wsL[kk * HH + jq * 4];    // contiguous
            a0.x += hv.x * wv.x; a0.y += hv.x * wv.y; a0.z += hv.x * wv.z; a0.w += hv.x * wv.w;
            a1.x += hv.y * wv.x; a1.y += hv.y * wv.y; a1.z += hv.y * wv.z; a1.w += hv.y * wv.w;
            a2.x += hv.z * wv.x; a2.y += hv.z * wv.y; a2.z += hv.z * wv.z; a2.w += hv.z * wv.w;
            a3.x += hv.w * wv.x; a3.y += hv.w * wv.y; a3.z += hv.w * wv.z; a3.w += hv.w * wv.w;
        }

        // ---- publish 16 floats = 8 relaxed agent 8B stores ----
        {
            const size_t base = pbase
                + ((size_t)(((destg << 3) + me) * 16 + (bq << 2)) << 5) + (joff >> 1);
            st8_agent(&ibx[base +  0], make_float2(a0.x, a0.y));
            st8_agent(&ibx[base +  1], make_float2(a0.z, a0.w));
            st8_agent(&ibx[base + 32], make_float2(a1.x, a1.y));
            st8_agent(&ibx[base + 33], make_float2(a1.z, a1.w));
            st8_agent(&ibx[base + 64], make_float2(a2.x, a2.y));
            st8_agent(&ibx[base + 65], make_float2(a2.z, a2.w));
            st8_agent(&ibx[base + 96], make_float2(a3.x, a3.y));
            st8_agent(&ibx[base + 97], make_float2(a3.z, a3.w));
        }

        // ---- release: drain own stores, then one flag (no cache maintenance) ----
        asm volatile("s_waitcnt vmcnt(0)" ::: "memory");
        __syncthreads();
        unsigned int* fl = flags + (t * NGRP + g) * 8;
        if (tid == 0)
            __hip_atomic_store(&fl[me], 1u, __ATOMIC_RELAXED, __HIP_MEMORY_SCOPE_AGENT);
        if (tid < 8) {
            while (__hip_atomic_load(&fl[tid], __ATOMIC_RELAXED,
                                     __HIP_MEMORY_SCOPE_AGENT) == 0u)
                __builtin_amdgcn_s_sleep(1);
        }
        __syncthreads();

        // ---- gather: 8 peers' partials for my 2 slots ----
        const size_t rb = pbase + ((size_t)((gid << 3) * 16 + b_loc) << 5) + (jl >> 1);
        float2 s = make_float2(0.f, 0.f);
        #pragma unroll
        for (int w = 0; w < 8; ++w) {
            const float2 v = ld8_agent(&ibx[rb + (size_t)w * 512]);
            s.x += v.x; s.y += v.y;
        }

        // ---- state update for my 2 (b, j) slots ----
        ah.x += DT * (s.x + x2.x - ah.x);
        ah.y += DT * (s.y + x2.y - ah.y);
        const float h0 = retanh_f(ah.x) + nz.x;
        const float h1 = retanh_f(ah.y) + nz.y;
        *(float2*)&hio[gidx] = make_float2(h0, h1);
        hsL[jl * HSPAD + b_loc]       = h0;
        hsL[(jl + 1) * HSPAD + b_loc] = h1;
        __syncthreads();   // hs updated before next step's GEMM
    }
}

// ---------------------------------------------------------------------------
// Kernel 3-fallback (Design C, proven round 3) — used if ws_size too small.
// ---------------------------------------------------------------------------
__global__ __launch_bounds__(512) void scan3_kernel(const float* __restrict__ Wr,
                                                    const float* __restrict__ noise,
                                                    const float* __restrict__ ah0,
                                                    float* __restrict__ hio) {
    extern __shared__ float4 part[];

    const int tid  = threadIdx.x;
    const int lane = tid & 63;
    const int w    = tid >> 6;
    const int b0   = blockIdx.x * MB;
    const int j    = (w << 6) + lane;

    const float4* Wv = (const float4*)Wr + (size_t)w * 8192 + lane;

    float ah[MB], hv[MB];
    {
        const float a0 = ah0[j];
        const float h0 = retanh_f(a0);
        #pragma unroll
        for (int b = 0; b < MB; ++b) { ah[b] = a0; hv[b] = h0; }
    }

    for (int t = 0; t < TT; ++t) {
        float x2[MB], nz[MB];
        #pragma unroll
        for (int b = 0; b < MB; ++b) {
            const int gidx = ((b0 + b) * TT + t) * HH + j;
            x2[b] = hio[gidx];
            nz[b] = noise[gidx];
        }

        float4 accA[MB], accB[MB];
        #pragma unroll
        for (int b = 0; b < MB; ++b) {
            accA[b] = make_float4(0.f, 0.f, 0.f, 0.f);
            accB[b] = make_float4(0.f, 0.f, 0.f, 0.f);
        }

        float4 wbA[8], wbB[8];
        const float4* pw = Wv;
        #pragma unroll
        for (int q = 0; q < 8; ++q) {
            wbA[q] = pw[q * 128];
            wbB[q] = pw[q * 128 + 64];
        }

        for (int blk = 0; blk < 7; ++blk) {
            #pragma unroll
            for (int q = 0; q < 8; ++q) {
                const int kk = (blk << 3) + q;
                const float4 wa = wbA[q];
                const float4 wb = wbB[q];
                wbA[q] = pw[(q + 8) * 128];
                wbB[q] = pw[(q + 8) * 128 + 64];
                #pragma unroll
                for (int b = 0; b < MB; ++b) {
                    const float s = readlane_f(hv[b], kk);
                    accA[b].x += s * wa.x; accA[b].y += s * wa.y;
                    accA[b].z += s * wa.z; accA[b].w += s * wa.w;
                    accB[b].x += s * wb.x; accB[b].y += s * wb.y;
                    accB[b].z += s * wb.z; accB[b].w += s * wb.w;
                }
            }
            pw += 1024;
        }
        #pragma unroll
        for (int q = 0; q < 8; ++q) {
            const int kk = 56 + q;
            const float4 wa = wbA[q];
            const float4 wb = wbB[q];
            #pragma unroll
            for (int b = 0; b < MB; ++b) {
                const float s = readlane_f(hv[b], kk);
                accA[b].x += s * wa.x; accA[b].y += s * wa.y;
                accA[b].z += s * wa.z; accA[b].w += s * wa.w;
                accB[b].x += s * wb.x; accB[b].y += s * wb.y;
                accB[b].z += s * wb.z; accB[b].w += s * wb.w;
            }
        }

        {
            float4* dst = part + (((size_t)(t & 1) * 8 + w) * 8) * 64 + lane;
            dst[0 * 64] = make_float4(accA[0].x, accA[1].x, accA[2].x, accA[3].x);
            dst[1 * 64] = make_float4(accA[0].y, accA[1].y, accA[2].y, accA[3].y);
            dst[2 * 64] = make_float4(accA[0].z, accA[1].z, accA[2].z, accA[3].z);
            dst[3 * 64] = make_float4(accA[0].w, accA[1].w, accA[2].w, accA[3].w);
            dst[4 * 64] = make_float4(accB[0].x, accB[1].x, accB[2].x, accB[3].x);
            dst[5 * 64] = make_float4(accB[0].y, accB[1].y, accB[2].y, accB[3].y);
            dst[6 * 64] = make_float4(accB[0].z, accB[1].z, accB[2].z, accB[3].z);
            dst[7 * 64] = make_float4(accB[0].w, accB[1].w, accB[2].w, accB[3].w);
        }
        __syncthreads();

        float4 sum;
        {
            const float4* src = part + ((size_t)(t & 1) * 64 + w) * 64 + lane;
            sum = src[0];
            #pragma unroll
            for (int v = 1; v < 8; ++v) {
                const float4 pv = src[(size_t)v * 512];
                sum.x += pv.x; sum.y += pv.y; sum.z += pv.z; sum.w += pv.w;
            }
        }

        const float sums[MB] = {sum.x, sum.y, sum.z, sum.w};
        #pragma unroll
        for (int b = 0; b < MB; ++b) {
            ah[b] += DT * (sums[b] + x2[b] - ah[b]);
            const float hn = retanh_f(ah[b]) + nz[b];
            hv[b] = hn;
            hio[((b0 + b) * TT + t) * HH + j] = hn;
        }
    }
}

// ---------------------------------------------------------------------------
// Kernel 4: tiny output projection
// ---------------------------------------------------------------------------
__global__ __launch_bounds__(256) void out_kernel(const float* __restrict__ hstore,
                                                  const float* __restrict__ Wy,
                                                  float* __restrict__ out0) {
    const int wave = threadIdx.x >> 6;
    const int lane = threadIdx.x & 63;
    const int r = blockIdx.x * 4 + wave;

    const float4* hv4 = (const float4*)&hstore[r * HH];
    float a0 = 0.0f, a1 = 0.0f;
    #pragma unroll
    for (int u = 0; u < 2; ++u) {
        const int e = u * 64 + lane;
        const float4 h  = hv4[e];
        const float4 w0 = *(const float4*)&Wy[e * 4];
        const float4 w1 = *(const float4*)&Wy[HH + e * 4];
        a0 += h.x * w0.x + h.y * w0.y + h.z * w0.z + h.w * w0.w;
        a1 += h.x * w1.x + h.y * w1.y + h.z * w1.z + h.w * w1.w;
    }
    #pragma unroll
    for (int off = 32; off > 0; off >>= 1) {
        a0 += __shfl_xor(a0, off);
        a1 += __shfl_xor(a1, off);
    }
    if (lane == 0) {
        out0[r * 2]     = a0;
        out0[r * 2 + 1] = a1;
    }
}

// ---------------------------------------------------------------------------
extern "C" void kernel_launch(void* const* d_in, const int* in_sizes, int n_in,
                              void* d_out, int out_size, void* d_ws, size_t ws_size,
                              hipStream_t stream) {
    const float* x     = (const float*)d_in[0];  // [B,T,DIN]
    const float* noise = (const float*)d_in[1];  // [B,T,H]
    const float* Wx    = (const float*)d_in[2];  // [H,DIN]
    const float* bah   = (const float*)d_in[3];  // [H]
    const float* Wh    = (const float*)d_in[4];  // [H,H]
    const float* Wy    = (const float*)d_in[5];  // [DOUT,H]
    const float* ah0   = (const float*)d_in[6];  // [H]

    float* out0   = (float*)d_out;                   // [B,T,DOUT]
    float* hstore = (float*)d_out + BB * TT * DOUTN; // [B,T,H]

    float* WxT  = (float*)d_ws;                      // [DIN,H]  1.05 MB
    float* Wsec = WxT + DIN * HH;                    // [H,H]    1.0 MB (WhT or Wr)
    float* inbox = Wsec + HH * HH;                   // 16 MB (2-parity inboxes)
    const size_t INBOX_F = (size_t)2 * 256 * 8 * 16 * 64;
    unsigned int* flags = (unsigned int*)(inbox + INBOX_F);  // 256 KB
    const size_t need = ((size_t)(DIN * HH + HH * HH) + INBOX_F
                         + (size_t)TT * NGRP * 8) * 4ull;
    const bool big = ws_size >= need;

    transpose_w<<<(DIN * HH + HH * HH + 255) / 256, 256, 0, stream>>>(
        Wx, Wh, WxT, Wsec, big ? 0 : 1);
    x2ah_kernel<<<BB * TT / 16, 256, 0, stream>>>(x, WxT, bah, hstore);

    if (big) {
        hipMemsetAsync(flags, 0, (size_t)TT * NGRP * 8 * sizeof(unsigned int), stream);
        const float* whtp = Wsec;
        float* hiop = hstore;
        float* ibp = inbox;
        unsigned int* flp = flags;
        void* args[] = { (void*)&whtp, (void*)&noise, (void*)&ah0,
                         (void*)&hiop, (void*)&ibp, (void*)&flp };
        hipLaunchCooperativeKernel((void*)scan4_kernel, dim3(NGRP * GW),
                                   dim3(512), args, 0, stream);
    } else {
        scan3_kernel<<<BB / MB, 512, 131072, stream>>>(Wsec, noise, ah0, hstore);
    }

    out_kernel<<<BB * TT / 4, 256, 0, stream>>>(hstore, Wy, out0);
}